// Round 10
// baseline (151.145 us; speedup 1.0000x reference)
//
#include <hip/hip_runtime.h>
#include <hip/hip_fp8.h>
#include <hip/hip_cooperative_groups.h>

#define N 8192
#define D 200
#define NSTEP 7            // 7 * 32 = 224 K fed to MFMA (200 real + fp8-zero pad)
#define TB 128             // tile edge (8 waves, 64x32 quadrant each)
#define NT 64              // tile grid dim = N/TB
#define TPP 65             // tiles per row-pair: row q has 64-q, row 63-q has q+1
#define NTILE 2080         // 32 * TPP triangle tiles
#define GRID 256           // persistent blocks: 1/CU, 2x margin on coop capacity
#define FSTEP 512          // bytes per fragment-step block (64 lanes x 8B)
#define PSTRIDE (NSTEP * FSTEP)        // 3584 B per 16-row panel
#define PANEL_T (8 * PSTRIDE)          // 28672 B per 128-row tile (contiguous)
#define XBSZ ((size_t)(N / 16) * PSTRIDE)  // 1.84 MB, L2-resident

// fallback (round-5 verbatim) parameters
#define KP 232
#define PANEL5 (TB * KP)   // 29696
#define NBLK5 2080
#define NCELL 256

typedef float f32x4 __attribute__((ext_vector_type(4)));
#define AS3 __attribute__((address_space(3)))
#define AS1 __attribute__((address_space(1)))

namespace cg = cooperative_groups;

// ==================== FUSED cooperative path ====================
// prep -> grid.sync -> chunked persistent gram (A-panel reuse) ->
// grid.sync -> block-0 reduce. Fragment-native xb layout (round-8
// verified): byte k of row r ->
//   (r/16)*3584 + (k/32)*512 + ((k%32)/8)*128 + (r%16)*8 + (k%8)
__global__ __launch_bounds__(512, 2) void fused_kernel(
    const float* __restrict__ x, const int* __restrict__ labels,
    unsigned char* __restrict__ xb, float* __restrict__ sq,
    int* __restrict__ lab, double* __restrict__ cells,
    float* __restrict__ out) {
  __shared__ __align__(16) unsigned char sA[PANEL_T];
  __shared__ __align__(16) unsigned char sB[PANEL_T];
  __shared__ double wsum[8];

  const int t = threadIdx.x;
  const int wid = t >> 6, lane = t & 63;
  const int b = blockIdx.x;

  // ---------- phase A: prep 32 rows per block (4 per wave) ----------
  {
    const int k0 = lane * 4;
#pragma unroll
    for (int r2 = 0; r2 < 4; ++r2) {
      const int row = b * 32 + wid * 4 + r2;           // 256*32 = 8192 exact
      const float* xr = x + (size_t)row * D;
      float4 f = {0.f, 0.f, 0.f, 0.f};
      if (k0 < D) f = *(const float4*)(xr + k0);       // lanes 0..49 in-bounds
      float s = 0.f;
      unsigned char qb[4];
      float ff[4] = {f.x, f.y, f.z, f.w};
#pragma unroll
      for (int c = 0; c < 4; ++c) {
        float v = (k0 + c < D) ? ff[c] : 0.f;
        __hip_fp8_e4m3 h(v);                           // OCP e4m3 RNE
        qb[c] = h.__x;
        float fb = (float)h;
        s += fb * fb;                                  // norm of fp8-rounded row
      }
      if (k0 < NSTEP * 32) {                           // lanes 0..55
        unsigned char* dst = xb + (size_t)(row >> 4) * PSTRIDE
                           + (k0 >> 5) * FSTEP + ((k0 & 31) >> 3) * 128
                           + (row & 15) * 8 + (k0 & 7);
        *(uchar4*)dst = *(uchar4*)qb;
      }
#pragma unroll
      for (int m = 32; m; m >>= 1) s += __shfl_xor(s, m);
      if (lane == 0) {
        sq[row] = s;
        lab[row] = labels[row];
      }
    }
  }

  cg::this_grid().sync();                              // xb/sq/lab grid-visible

  // ---------- phase B: chunked gram, A-panel staged only on change ----------
  const int col = lane & 15, quad = lane >> 4;
  const int waveM = (wid & 1) * 64, waveN = (wid >> 1) * 32;
  const int pA = (waveM >> 4) * PSTRIDE + lane * 8;    // conflict-free ds bases
  const int pB = (waveN >> 4) * PSTRIDE + lane * 8;

  const int base = b * 8 + (b < 32 ? b : 32);          // blocks 0..31 take 9 tiles
  const int cnt = 8 + (b < 32 ? 1 : 0);                // 32*9 + 224*8 = 2080
  float tot = 0.f;
  int curI = -1;

  for (int k = 0; k < cnt; ++k) {
    const int tt = base + k;
    const int q = tt / TPP, idx = tt - q * TPP;        // row-pair decode
    const int n1 = NT - q;
    const int I = (idx < n1) ? q : NT - 1 - q;
    const int J = (idx < n1) ? q + idx : (NT - 1 - q) + (idx - n1);

    __syncthreads();                                   // all done with sA/sB
    if (I != curI) {                                   // rare: stage A panel
      const unsigned char* gA = xb + (size_t)(8 * I) * PSTRIDE;
#pragma unroll
      for (int c = 0; c < 3; ++c) {
        int off = c * 8192 + t * 16;
        __builtin_amdgcn_global_load_lds((const AS1 void*)(gA + off),
                                         (AS3 void*)(sA + off), 16, 0, 0);
      }
      if (t < 256) {
        int off = 24576 + t * 16;
        __builtin_amdgcn_global_load_lds((const AS1 void*)(gA + off),
                                         (AS3 void*)(sA + off), 16, 0, 0);
      }
      curI = I;
    }
    {                                                  // stage B panel
      const unsigned char* gB = xb + (size_t)(8 * J) * PSTRIDE;
#pragma unroll
      for (int c = 0; c < 3; ++c) {
        int off = c * 8192 + t * 16;
        __builtin_amdgcn_global_load_lds((const AS1 void*)(gB + off),
                                         (AS3 void*)(sB + off), 16, 0, 0);
      }
      if (t < 256) {
        int off = 24576 + t * 16;
        __builtin_amdgcn_global_load_lds((const AS1 void*)(gB + off),
                                         (AS3 void*)(sB + off), 16, 0, 0);
      }
    }

    // hoisted epilogue operands (ride the same vmcnt drain as staging)
    const int i0 = I * TB + waveM, j0 = J * TB + waveN;
    int labj[2];
    float sqj[2];
#pragma unroll
    for (int ni = 0; ni < 2; ++ni) {
      int j = j0 + ni * 16 + col;
      labj[ni] = lab[j];
      sqj[ni] = sq[j];
    }
    float4 sqi4[4];
    int4 li4[4];
#pragma unroll
    for (int mi = 0; mi < 4; ++mi) {
      sqi4[mi] = *(const float4*)(sq + i0 + mi * 16 + quad * 4);
      li4[mi] = *(const int4*)(lab + i0 + mi * 16 + quad * 4);
    }
    __syncthreads();                                   // drain staging + barrier

    // K-loop from LDS: conflict-free ds_read_b64, compile-time offsets
    f32x4 acc[4][2] = {};
    __builtin_amdgcn_s_setprio(1);
#pragma unroll
    for (int step = 0; step < NSTEP; ++step) {
      long a[4], bf[2];
#pragma unroll
      for (int mi = 0; mi < 4; ++mi)
        a[mi] = *(const long*)(sA + pA + mi * PSTRIDE + step * FSTEP);
#pragma unroll
      for (int ni = 0; ni < 2; ++ni)
        bf[ni] = *(const long*)(sB + pB + ni * PSTRIDE + step * FSTEP);
#pragma unroll
      for (int mi = 0; mi < 4; ++mi)
#pragma unroll
        for (int ni = 0; ni < 2; ++ni)
          acc[mi][ni] = __builtin_amdgcn_mfma_f32_16x16x32_fp8_fp8(
              a[mi], bf[ni], acc[mi][ni], 0, 0, 0);
    }
    __builtin_amdgcn_s_setprio(0);

    // epilogue: D[m = quad*4 + r][n = col] (verified layout)
    float rs = 0.f;
    if (I != J) {
#pragma unroll
      for (int mi = 0; mi < 4; ++mi) {
        float sqi[4] = {sqi4[mi].x, sqi4[mi].y, sqi4[mi].z, sqi4[mi].w};
        int li[4] = {li4[mi].x, li4[mi].y, li4[mi].z, li4[mi].w};
#pragma unroll
        for (int r = 0; r < 4; ++r)
#pragma unroll
          for (int ni = 0; ni < 2; ++ni) {
            float g = acc[mi][ni][r];
            float d2 = fmaxf(fmaf(-2.f, g, sqi[r] + sqj[ni]), 0.f);
            float dist = __builtin_amdgcn_sqrtf(d2);
            rs += (li[r] == labj[ni]) ? dist : -dist;
          }
      }
      tot += 2.f * rs;                                 // mirror tile not launched
    } else {
#pragma unroll
      for (int mi = 0; mi < 4; ++mi) {
        float sqi[4] = {sqi4[mi].x, sqi4[mi].y, sqi4[mi].z, sqi4[mi].w};
        int li[4] = {li4[mi].x, li4[mi].y, li4[mi].z, li4[mi].w};
#pragma unroll
        for (int r = 0; r < 4; ++r) {
          int gi = i0 + mi * 16 + quad * 4 + r;
#pragma unroll
          for (int ni = 0; ni < 2; ++ni) {
            int gj = j0 + ni * 16 + col;
            float g = acc[mi][ni][r];
            float d2 = fmaxf(fmaf(-2.f, g, sqi[r] + sqj[ni]), 0.f);
            float dist = __builtin_amdgcn_sqrtf(d2);
            float c = (li[r] == labj[ni]) ? dist : -dist;
            rs += (gi == gj) ? 0.f : c;
          }
        }
      }
      tot += rs;
    }
  }

  // ---------- block partial: plain store, no atomics ----------
#pragma unroll
  for (int m = 32; m; m >>= 1) tot += __shfl_xor(tot, m);
  if (lane == 0) wsum[wid] = (double)tot;
  __syncthreads();
  if (t == 0) {
    double bs = 0.0;
#pragma unroll
    for (int i2 = 0; i2 < 8; ++i2) bs += wsum[i2];
    cells[b] = bs;
  }

  cg::this_grid().sync();                              // partials grid-visible

  if (b == 0) {                                        // final reduce: 256 doubles
    double s = (t < GRID) ? atomicAdd(&cells[t], 0.0) : 0.0;  // coherent read
#pragma unroll
    for (int m = 32; m; m >>= 1) s += __shfl_xor(s, m);
    if (lane == 0) wsum[wid] = s;
    __syncthreads();
    if (t == 0) {
      double fs = 0.0;
#pragma unroll
      for (int i2 = 0; i2 < 8; ++i2) fs += wsum[i2];
      out[0] = (float)(fs / (double)N);
    }
  }
}

// ==================== FALLBACK: round-5 verbatim (82.3 us, absmax 0) ====================
__global__ __launch_bounds__(256) void prep5_kernel(
    const float* __restrict__ x, const int* __restrict__ labels,
    unsigned char* __restrict__ xb, float* __restrict__ sq,
    int* __restrict__ lab, double* __restrict__ cells) {
  if (blockIdx.x == 0) cells[threadIdx.x] = 0.0;
  int row = blockIdx.x * 4 + (threadIdx.x >> 6);
  int lane = threadIdx.x & 63;
  const float* xr = x + (size_t)row * D;
  unsigned char* xbr = xb + (size_t)row * KP;
  int k0 = lane * 4;
  float4 f = {0.f, 0.f, 0.f, 0.f};
  if (k0 < D) f = *(const float4*)(xr + k0);
  float s = 0.f;
  unsigned char q[4];
  float ff[4] = {f.x, f.y, f.z, f.w};
#pragma unroll
  for (int c = 0; c < 4; ++c) {
    float v = (k0 + c < D) ? ff[c] : 0.f;
    __hip_fp8_e4m3 h(v);
    q[c] = h.__x;
    float fb = (float)h;
    s += fb * fb;
  }
  if (k0 < KP) *(uchar4*)(xbr + k0) = *(uchar4*)q;
#pragma unroll
  for (int m = 32; m; m >>= 1) s += __shfl_xor(s, m);
  if (lane == 0) {
    sq[row] = s;
    lab[row] = labels[row];
  }
}

__global__ __launch_bounds__(256, 2) void gram5_kernel(
    const unsigned char* __restrict__ xb, const float* __restrict__ sq,
    const int* __restrict__ lab, double* __restrict__ cells) {
  __shared__ __align__(16) unsigned char sA[PANEL5];
  __shared__ __align__(16) unsigned char sB[PANEL5];
  const int t = threadIdx.x;
  const int b = (blockIdx.x & 7) * (NBLK5 / 8) + (blockIdx.x >> 3);
  const int q = b / TPP, idx = b - q * TPP;
  const int n1 = NT - q;
  const int I = (idx < n1) ? q : NT - 1 - q;
  const int J = (idx < n1) ? q + idx : (NT - 1 - q) + (idx - n1);
  auto stage = [&](const unsigned char* g, unsigned char* sh) {
#pragma unroll
    for (int c = 0; c < 7; ++c) {
      int off = c * 4096 + t * 16;
      __builtin_amdgcn_global_load_lds((const AS1 void*)(g + off),
                                       (AS3 void*)(sh + off), 16, 0, 0);
    }
    if (t < 64) {
      int off = 28672 + t * 16;
      __builtin_amdgcn_global_load_lds((const AS1 void*)(g + off),
                                       (AS3 void*)(sh + off), 16, 0, 0);
    }
  };
  stage(xb + (size_t)I * PANEL5, sA);
  stage(xb + (size_t)J * PANEL5, sB);
  const int wid = t >> 6, lane = t & 63;
  const int col = lane & 15, quad = lane >> 4;
  const int waveM = (wid >> 1) * 64, waveN = (wid & 1) * 64;
  const int i0 = I * TB + waveM, j0 = J * TB + waveN;
  int labj[4];
  float sqj[4];
#pragma unroll
  for (int ni = 0; ni < 4; ++ni) {
    int j = j0 + ni * 16 + col;
    labj[ni] = lab[j];
    sqj[ni] = sq[j];
  }
  float4 sqi4[4];
  int4 li4[4];
#pragma unroll
  for (int mi = 0; mi < 4; ++mi) {
    sqi4[mi] = *(const float4*)(sq + i0 + mi * 16 + quad * 4);
    li4[mi] = *(const int4*)(lab + i0 + mi * 16 + quad * 4);
  }
  __syncthreads();
  f32x4 acc[4][4] = {};
  __builtin_amdgcn_s_setprio(1);
#pragma unroll
  for (int step = 0; step < NSTEP; ++step) {
    long a[4], bf[4];
#pragma unroll
    for (int mi = 0; mi < 4; ++mi)
      a[mi] = *(const long*)(sA + (waveM + mi * 16 + col) * KP + step * 32 + quad * 8);
#pragma unroll
    for (int ni = 0; ni < 4; ++ni)
      bf[ni] = *(const long*)(sB + (waveN + ni * 16 + col) * KP + step * 32 + quad * 8);
#pragma unroll
    for (int mi = 0; mi < 4; ++mi)
#pragma unroll
      for (int ni = 0; ni < 4; ++ni)
        acc[mi][ni] = __builtin_amdgcn_mfma_f32_16x16x32_fp8_fp8(
            a[mi], bf[ni], acc[mi][ni], 0, 0, 0);
  }
  __builtin_amdgcn_s_setprio(0);
  float rs = 0.f, tot;
  if (I != J) {
#pragma unroll
    for (int mi = 0; mi < 4; ++mi) {
      float sqi[4] = {sqi4[mi].x, sqi4[mi].y, sqi4[mi].z, sqi4[mi].w};
      int li[4] = {li4[mi].x, li4[mi].y, li4[mi].z, li4[mi].w};
#pragma unroll
      for (int r = 0; r < 4; ++r)
#pragma unroll
        for (int ni = 0; ni < 4; ++ni) {
          float g = acc[mi][ni][r];
          float d2 = fmaxf(fmaf(-2.f, g, sqi[r] + sqj[ni]), 0.f);
          float dist = __builtin_amdgcn_sqrtf(d2);
          rs += (li[r] == labj[ni]) ? dist : -dist;
        }
    }
    tot = 2.f * rs;
  } else {
#pragma unroll
    for (int mi = 0; mi < 4; ++mi) {
      float sqi[4] = {sqi4[mi].x, sqi4[mi].y, sqi4[mi].z, sqi4[mi].w};
      int li[4] = {li4[mi].x, li4[mi].y, li4[mi].z, li4[mi].w};
#pragma unroll
      for (int r = 0; r < 4; ++r) {
        int i = i0 + mi * 16 + quad * 4 + r;
#pragma unroll
        for (int ni = 0; ni < 4; ++ni) {
          int j = j0 + ni * 16 + col;
          float g = acc[mi][ni][r];
          float d2 = fmaxf(fmaf(-2.f, g, sqi[r] + sqj[ni]), 0.f);
          float dist = __builtin_amdgcn_sqrtf(d2);
          float c = (li[r] == labj[ni]) ? dist : -dist;
          rs += (i == j) ? 0.f : c;
        }
      }
    }
    tot = rs;
  }
#pragma unroll
  for (int m = 32; m; m >>= 1) tot += __shfl_xor(tot, m);
  if (lane == 0)
    atomicAdd(&cells[(b * 4 + wid) & (NCELL - 1)], (double)tot);
}

__global__ __launch_bounds__(256) void reduce5_kernel(
    const double* __restrict__ cells, float* __restrict__ out) {
  __shared__ double wsum[4];
  double s = cells[threadIdx.x];
#pragma unroll
  for (int m = 32; m; m >>= 1) s += __shfl_xor(s, m);
  if ((threadIdx.x & 63) == 0) wsum[threadIdx.x >> 6] = s;
  __syncthreads();
  if (threadIdx.x == 0)
    out[0] = (float)((wsum[0] + wsum[1] + wsum[2] + wsum[3]) / (double)N);
}

extern "C" void kernel_launch(void* const* d_in, const int* in_sizes, int n_in,
                              void* d_out, int out_size, void* d_ws, size_t ws_size,
                              hipStream_t stream) {
  const float* x = (const float*)d_in[0];
  const int* labels = (const int*)d_in[1];
  char* ws = (char*)d_ws;
  float* out = (float*)d_out;

  // fused-path workspace layout (fragment-native xb)
  unsigned char* xb = (unsigned char*)ws;                      // XBSZ = 1.84 MB
  float* sq = (float*)(ws + XBSZ);
  int* lab = (int*)(ws + XBSZ + (size_t)N * 4);
  double* cells = (double*)(ws + XBSZ + (size_t)N * 8);        // GRID*8

  void* args[7] = {(void*)&x, (void*)&labels, (void*)&xb, (void*)&sq,
                   (void*)&lab, (void*)&cells, (void*)&out};
  hipError_t e = hipLaunchCooperativeKernel((void*)fused_kernel, dim3(GRID),
                                            dim3(512), args, 0, stream);
  if (e != hipSuccess) {
    // proven 3-kernel path (round 5: 82.3 us, absmax 0.0)
    unsigned char* xb5 = (unsigned char*)ws;                   // N*KP = 1.9 MB
    float* sq5 = (float*)(ws + (size_t)N * KP);
    int* lab5 = (int*)(ws + (size_t)N * KP + (size_t)N * 4);
    double* cells5 = (double*)(ws + (size_t)N * KP + (size_t)N * 8);
    prep5_kernel<<<N / 4, 256, 0, stream>>>(x, labels, xb5, sq5, lab5, cells5);
    gram5_kernel<<<NBLK5, 256, 0, stream>>>(xb5, sq5, lab5, cells5);
    reduce5_kernel<<<1, 256, 0, stream>>>(cells5, out);
  }
}

// Round 11
// 111.379 us; speedup vs baseline: 1.3570x; 1.3570x over previous
//
#include <hip/hip_runtime.h>
#include <hip/hip_fp8.h>

#define N 8192
#define D 200
#define KP 232             // fp8 row stride BYTES: 58 dwords, gcd(58,32)=2 -> low LDS aliasing
#define NSTEP 7            // 7 * 32 = 224 K fed to MFMA (200 real + fp8-zero pad)
#define TB 128             // tile edge, ONE TILE PER BLOCK (4 waves, 64x64 quadrant each)
#define NT 64              // tile grid dim = N/TB
#define TPP 65             // tiles per row-pair: row q has 64-q, row 63-q has q+1
#define NBLK (32 * TPP)    // 2080 triangle tiles == blocks (2080 % 8 == 0)
#define PANEL (TB * KP)    // 29696 B, contiguous in global AND in LDS
#define NCELL 256

typedef float f32x4 __attribute__((ext_vector_type(4)));
#define AS3 __attribute__((address_space(3)))
#define AS1 __attribute__((address_space(1)))

// ---- prep: cast to fp8 e4m3 (padded to KP), row norms from fp8-decoded ----
// Block 0 zeroes the 256 reduction cells + the ticket counter.
__global__ __launch_bounds__(256) void prep_kernel(
    const float* __restrict__ x, const int* __restrict__ labels,
    unsigned char* __restrict__ xb, float* __restrict__ sq,
    int* __restrict__ lab, double* __restrict__ cells,
    unsigned int* __restrict__ counter) {
  if (blockIdx.x == 0) {
    cells[threadIdx.x] = 0.0;                      // NCELL == blockDim
    if (threadIdx.x == 0) *counter = 0u;
  }
  int row = blockIdx.x * 4 + (threadIdx.x >> 6);   // one wave per row
  int lane = threadIdx.x & 63;
  const float* xr = x + (size_t)row * D;
  unsigned char* xbr = xb + (size_t)row * KP;
  int k0 = lane * 4;
  float4 f = {0.f, 0.f, 0.f, 0.f};
  if (k0 < D) f = *(const float4*)(xr + k0);       // lane<50 fully in-bounds
  float s = 0.f;
  unsigned char q[4];
  float ff[4] = {f.x, f.y, f.z, f.w};
#pragma unroll
  for (int c = 0; c < 4; ++c) {
    float v = (k0 + c < D) ? ff[c] : 0.f;
    __hip_fp8_e4m3 h(v);                           // OCP e4m3 RNE
    q[c] = h.__x;
    float fb = (float)h;
    s += fb * fb;                                  // norm of the fp8-rounded row
  }
  if (k0 < KP) *(uchar4*)(xbr + k0) = *(uchar4*)q; // lanes 0..57 (56,57 write zeros)
#pragma unroll
  for (int m = 32; m; m >>= 1) s += __shfl_xor(s, m);
  if (lane == 0) {
    sq[row] = s;
    lab[row] = labels[row];
  }
}

// ---- gram: round-5 verbatim body (session best: 82.3 us, absmax 0.0),
// ---- plus fused final reduction via the round-1-verified ticket pattern
// ---- (per-block single cell atomic -> threadfence -> ticket -> last block
// ---- atomically re-reads 256 cells and writes out). Removes the reduce
// ---- dispatch and its gap.
__global__ __launch_bounds__(256, 2) void gram_kernel(
    const unsigned char* __restrict__ xb, const float* __restrict__ sq,
    const int* __restrict__ lab, double* __restrict__ cells,
    unsigned int* __restrict__ counter, float* __restrict__ out) {
  __shared__ __align__(16) unsigned char sA[PANEL];
  __shared__ __align__(16) unsigned char sB[PANEL];
  __shared__ double wsum[4];
  __shared__ int lastFlag;

  const int t = threadIdx.x;
  const int b = (blockIdx.x & 7) * (NBLK / 8) + (blockIdx.x >> 3);  // XCD swizzle (2080%8==0)
  const int q = b / TPP, idx = b - q * TPP;        // row-pair decode
  const int n1 = NT - q;
  const int I = (idx < n1) ? q : NT - 1 - q;
  const int J = (idx < n1) ? q + idx : (NT - 1 - q) + (idx - n1);

  auto stage = [&](const unsigned char* g, unsigned char* sh) {
#pragma unroll
    for (int c = 0; c < 7; ++c) {
      int off = c * 4096 + t * 16;
      __builtin_amdgcn_global_load_lds((const AS1 void*)(g + off),
                                       (AS3 void*)(sh + off), 16, 0, 0);
    }
    if (t < 64) {
      int off = 28672 + t * 16;
      __builtin_amdgcn_global_load_lds((const AS1 void*)(g + off),
                                       (AS3 void*)(sh + off), 16, 0, 0);
    }
  };
  stage(xb + (size_t)I * PANEL, sA);
  stage(xb + (size_t)J * PANEL, sB);

  // ---- hoisted epilogue operands (ride the same vmcnt drain as staging) ----
  const int wid = t >> 6, lane = t & 63;
  const int col = lane & 15, quad = lane >> 4;
  const int waveM = (wid >> 1) * 64, waveN = (wid & 1) * 64;
  const int i0 = I * TB + waveM, j0 = J * TB + waveN;
  int labj[4];
  float sqj[4];
#pragma unroll
  for (int ni = 0; ni < 4; ++ni) {
    int j = j0 + ni * 16 + col;
    labj[ni] = lab[j];
    sqj[ni] = sq[j];
  }
  float4 sqi4[4];
  int4 li4[4];
#pragma unroll
  for (int mi = 0; mi < 4; ++mi) {
    sqi4[mi] = *(const float4*)(sq + i0 + mi * 16 + quad * 4);
    li4[mi] = *(const int4*)(lab + i0 + mi * 16 + quad * 4);
  }
  __syncthreads();                                 // drains staging vmcnt + barrier

  // ---- K-loop from LDS ----
  f32x4 acc[4][4] = {};
  __builtin_amdgcn_s_setprio(1);
#pragma unroll
  for (int step = 0; step < NSTEP; ++step) {
    long a[4], bf[4];
#pragma unroll
    for (int mi = 0; mi < 4; ++mi)
      a[mi] = *(const long*)(sA + (waveM + mi * 16 + col) * KP + step * 32 + quad * 8);
#pragma unroll
    for (int ni = 0; ni < 4; ++ni)
      bf[ni] = *(const long*)(sB + (waveN + ni * 16 + col) * KP + step * 32 + quad * 8);
#pragma unroll
    for (int mi = 0; mi < 4; ++mi)
#pragma unroll
      for (int ni = 0; ni < 4; ++ni)
        acc[mi][ni] = __builtin_amdgcn_mfma_f32_16x16x32_fp8_fp8(
            a[mi], bf[ni], acc[mi][ni], 0, 0, 0);
  }
  __builtin_amdgcn_s_setprio(0);

  // ---- epilogue: D[m = quad*4 + r][n = col] (verified layout) ----
  float rs = 0.f, tot;
  if (I != J) {
#pragma unroll
    for (int mi = 0; mi < 4; ++mi) {
      float sqi[4] = {sqi4[mi].x, sqi4[mi].y, sqi4[mi].z, sqi4[mi].w};
      int li[4] = {li4[mi].x, li4[mi].y, li4[mi].z, li4[mi].w};
#pragma unroll
      for (int r = 0; r < 4; ++r)
#pragma unroll
        for (int ni = 0; ni < 4; ++ni) {
          float g = acc[mi][ni][r];
          float d2 = fmaxf(fmaf(-2.f, g, sqi[r] + sqj[ni]), 0.f);
          float dist = __builtin_amdgcn_sqrtf(d2);
          rs += (li[r] == labj[ni]) ? dist : -dist;
        }
    }
    tot = 2.f * rs;                                // mirror tile not launched
  } else {
#pragma unroll
    for (int mi = 0; mi < 4; ++mi) {
      float sqi[4] = {sqi4[mi].x, sqi4[mi].y, sqi4[mi].z, sqi4[mi].w};
      int li[4] = {li4[mi].x, li4[mi].y, li4[mi].z, li4[mi].w};
#pragma unroll
      for (int r = 0; r < 4; ++r) {
        int i = i0 + mi * 16 + quad * 4 + r;
#pragma unroll
        for (int ni = 0; ni < 4; ++ni) {
          int j = j0 + ni * 16 + col;
          float g = acc[mi][ni][r];
          float d2 = fmaxf(fmaf(-2.f, g, sqi[r] + sqj[ni]), 0.f);
          float dist = __builtin_amdgcn_sqrtf(d2);
          float c = (li[r] == labj[ni]) ? dist : -dist;
          rs += (i == j) ? 0.f : c;
        }
      }
    }
    tot = rs;
  }

  // ---- block reduce + fused grid reduction (round-1-verified pattern) ----
#pragma unroll
  for (int m = 32; m; m >>= 1) tot += __shfl_xor(tot, m);
  if (lane == 0) wsum[wid] = (double)tot;
  __syncthreads();
  if (t == 0) {
    double bs = wsum[0] + wsum[1] + wsum[2] + wsum[3];
    atomicAdd(&cells[b & (NCELL - 1)], bs);        // ~8 blocks/cell
    __threadfence();                               // publish before the ticket
    unsigned int old = atomicAdd(counter, 1u);
    lastFlag = (old == NBLK - 1) ? 1 : 0;
  }
  __syncthreads();
  if (lastFlag) {                                  // uniform per block
    double s = atomicAdd(&cells[t], 0.0);          // atomic read: XCD-coherent
#pragma unroll
    for (int m = 32; m; m >>= 1) s += __shfl_xor(s, m);
    if (lane == 0) wsum[wid] = s;
    __syncthreads();
    if (t == 0)
      out[0] = (float)((wsum[0] + wsum[1] + wsum[2] + wsum[3]) / (double)N);
  }
}

extern "C" void kernel_launch(void* const* d_in, const int* in_sizes, int n_in,
                              void* d_out, int out_size, void* d_ws, size_t ws_size,
                              hipStream_t stream) {
  const float* x = (const float*)d_in[0];
  const int* labels = (const int*)d_in[1];
  char* ws = (char*)d_ws;
  unsigned char* xb = (unsigned char*)ws;                               // N*KP = 1.9 MB
  float* sq = (float*)(ws + (size_t)N * KP);                            // N*4
  int* lab = (int*)(ws + (size_t)N * KP + (size_t)N * 4);               // N*4
  double* cells = (double*)(ws + (size_t)N * KP + (size_t)N * 8);       // 256*8
  unsigned int* counter =
      (unsigned int*)(ws + (size_t)N * KP + (size_t)N * 8 + NCELL * 8);
  float* out = (float*)d_out;

  prep_kernel<<<N / 4, 256, 0, stream>>>(x, labels, xb, sq, lab, cells, counter);
  gram_kernel<<<NBLK, 256, 0, stream>>>(xb, sq, lab, cells, counter, out);
}

// Round 12
// 82.561 us; speedup vs baseline: 1.8307x; 1.3490x over previous
//
#include <hip/hip_runtime.h>
#include <hip/hip_fp8.h>

#define N 8192
#define D 200
#define KP 232             // fp8 row stride BYTES: 58 dwords, gcd(58,32)=2 -> low LDS aliasing
#define NSTEP 7            // 7 * 32 = 224 K fed to MFMA (200 real + fp8-zero pad)
#define TB 128             // tile edge, ONE TILE PER BLOCK (4 waves, 64x64 quadrant each)
#define NT 64              // tile grid dim = N/TB
#define TPP 65             // tiles per row-pair: row q has 64-q, row 63-q has q+1
#define NBLK (32 * TPP)    // 2080 triangle tiles == blocks (2080 % 8 == 0)
#define PANEL (TB * KP)    // 29696 B, contiguous in global AND in LDS
#define NCELL 256

typedef float f32x4 __attribute__((ext_vector_type(4)));
#define AS3 __attribute__((address_space(3)))
#define AS1 __attribute__((address_space(1)))

// ---- prep: cast to fp8 e4m3 (padded to KP), row norms from fp8-decoded ----
// Block 0 also zeroes the 256 reduction cells (workspace is poisoned each iter).
__global__ __launch_bounds__(256) void prep_kernel(
    const float* __restrict__ x, const int* __restrict__ labels,
    unsigned char* __restrict__ xb, float* __restrict__ sq,
    int* __restrict__ lab, double* __restrict__ cells) {
  if (blockIdx.x == 0) cells[threadIdx.x] = 0.0;   // NCELL == blockDim
  int row = blockIdx.x * 4 + (threadIdx.x >> 6);   // one wave per row
  int lane = threadIdx.x & 63;
  const float* xr = x + (size_t)row * D;
  unsigned char* xbr = xb + (size_t)row * KP;
  int k0 = lane * 4;
  float4 f = {0.f, 0.f, 0.f, 0.f};
  if (k0 < D) f = *(const float4*)(xr + k0);       // lane<50 fully in-bounds
  float s = 0.f;
  unsigned char q[4];
  float ff[4] = {f.x, f.y, f.z, f.w};
#pragma unroll
  for (int c = 0; c < 4; ++c) {
    float v = (k0 + c < D) ? ff[c] : 0.f;
    __hip_fp8_e4m3 h(v);                           // OCP e4m3 RNE
    q[c] = h.__x;
    float fb = (float)h;
    s += fb * fb;                                  // norm of the fp8-rounded row
  }
  if (k0 < KP) *(uchar4*)(xbr + k0) = *(uchar4*)q; // lanes 0..57 (56,57 write zeros)
#pragma unroll
  for (int m = 32; m; m >>= 1) s += __shfl_xor(s, m);
  if (lane == 0) {
    sq[row] = s;
    lab[row] = labels[row];
  }
}

// ---- gram: one 128x128 tile per block; global_load_lds staging; hoisted
// ---- epilogue operands; per-wave scatter atomics into 256 cells (NO
// ---- ticket/fence finish — round 11 measured that at +27 us). Session-best
// ---- configuration (round 5: 82.3 us, absmax 0.0).
__global__ __launch_bounds__(256, 2) void gram_kernel(
    const unsigned char* __restrict__ xb, const float* __restrict__ sq,
    const int* __restrict__ lab, double* __restrict__ cells) {
  __shared__ __align__(16) unsigned char sA[PANEL];
  __shared__ __align__(16) unsigned char sB[PANEL];

  const int t = threadIdx.x;
  const int b = (blockIdx.x & 7) * (NBLK / 8) + (blockIdx.x >> 3);  // XCD swizzle (2080%8==0)
  const int q = b / TPP, idx = b - q * TPP;        // row-pair decode
  const int n1 = NT - q;
  const int I = (idx < n1) ? q : NT - 1 - q;
  const int J = (idx < n1) ? q + idx : (NT - 1 - q) + (idx - n1);

  auto stage = [&](const unsigned char* g, unsigned char* sh) {
#pragma unroll
    for (int c = 0; c < 7; ++c) {
      int off = c * 4096 + t * 16;
      __builtin_amdgcn_global_load_lds((const AS1 void*)(g + off),
                                       (AS3 void*)(sh + off), 16, 0, 0);
    }
    if (t < 64) {
      int off = 28672 + t * 16;
      __builtin_amdgcn_global_load_lds((const AS1 void*)(g + off),
                                       (AS3 void*)(sh + off), 16, 0, 0);
    }
  };
  stage(xb + (size_t)I * PANEL, sA);
  stage(xb + (size_t)J * PANEL, sB);

  // ---- hoisted epilogue operands (ride the same vmcnt drain as staging) ----
  const int wid = t >> 6, lane = t & 63;
  const int col = lane & 15, quad = lane >> 4;
  const int waveM = (wid >> 1) * 64, waveN = (wid & 1) * 64;
  const int i0 = I * TB + waveM, j0 = J * TB + waveN;
  int labj[4];
  float sqj[4];
#pragma unroll
  for (int ni = 0; ni < 4; ++ni) {
    int j = j0 + ni * 16 + col;
    labj[ni] = lab[j];
    sqj[ni] = sq[j];
  }
  float4 sqi4[4];
  int4 li4[4];
#pragma unroll
  for (int mi = 0; mi < 4; ++mi) {
    sqi4[mi] = *(const float4*)(sq + i0 + mi * 16 + quad * 4);
    li4[mi] = *(const int4*)(lab + i0 + mi * 16 + quad * 4);
  }
  __syncthreads();                                 // drains staging vmcnt + barrier

  // ---- K-loop from LDS ----
  f32x4 acc[4][4] = {};
  __builtin_amdgcn_s_setprio(1);
#pragma unroll
  for (int step = 0; step < NSTEP; ++step) {
    long a[4], bf[4];
#pragma unroll
    for (int mi = 0; mi < 4; ++mi)
      a[mi] = *(const long*)(sA + (waveM + mi * 16 + col) * KP + step * 32 + quad * 8);
#pragma unroll
    for (int ni = 0; ni < 4; ++ni)
      bf[ni] = *(const long*)(sB + (waveN + ni * 16 + col) * KP + step * 32 + quad * 8);
#pragma unroll
    for (int mi = 0; mi < 4; ++mi)
#pragma unroll
      for (int ni = 0; ni < 4; ++ni)
        acc[mi][ni] = __builtin_amdgcn_mfma_f32_16x16x32_fp8_fp8(
            a[mi], bf[ni], acc[mi][ni], 0, 0, 0);
  }
  __builtin_amdgcn_s_setprio(0);

  // ---- epilogue: D[m = quad*4 + r][n = col] (verified layout) ----
  float rs = 0.f, tot;
  if (I != J) {
#pragma unroll
    for (int mi = 0; mi < 4; ++mi) {
      float sqi[4] = {sqi4[mi].x, sqi4[mi].y, sqi4[mi].z, sqi4[mi].w};
      int li[4] = {li4[mi].x, li4[mi].y, li4[mi].z, li4[mi].w};
#pragma unroll
      for (int r = 0; r < 4; ++r)
#pragma unroll
        for (int ni = 0; ni < 4; ++ni) {
          float g = acc[mi][ni][r];
          float d2 = fmaxf(fmaf(-2.f, g, sqi[r] + sqj[ni]), 0.f);
          float dist = __builtin_amdgcn_sqrtf(d2);
          rs += (li[r] == labj[ni]) ? dist : -dist;
        }
    }
    tot = 2.f * rs;                                // mirror tile not launched
  } else {
#pragma unroll
    for (int mi = 0; mi < 4; ++mi) {
      float sqi[4] = {sqi4[mi].x, sqi4[mi].y, sqi4[mi].z, sqi4[mi].w};
      int li[4] = {li4[mi].x, li4[mi].y, li4[mi].z, li4[mi].w};
#pragma unroll
      for (int r = 0; r < 4; ++r) {
        int i = i0 + mi * 16 + quad * 4 + r;
#pragma unroll
        for (int ni = 0; ni < 4; ++ni) {
          int j = j0 + ni * 16 + col;
          float g = acc[mi][ni][r];
          float d2 = fmaxf(fmaf(-2.f, g, sqi[r] + sqj[ni]), 0.f);
          float dist = __builtin_amdgcn_sqrtf(d2);
          float c = (li[r] == labj[ni]) ? dist : -dist;
          rs += (i == j) ? 0.f : c;
        }
      }
    }
    tot = rs;
  }

  // ---- per-wave f64 scatter atomic (256 cells: no contention) ----
#pragma unroll
  for (int m = 32; m; m >>= 1) tot += __shfl_xor(tot, m);
  if (lane == 0)
    atomicAdd(&cells[(b * 4 + wid) & (NCELL - 1)], (double)tot);
}

// ---------------- final mean (256 doubles only) ----------------
__global__ __launch_bounds__(256) void reduce_kernel(
    const double* __restrict__ cells, float* __restrict__ out) {
  __shared__ double wsum[4];
  double s = cells[threadIdx.x];
#pragma unroll
  for (int m = 32; m; m >>= 1) s += __shfl_xor(s, m);
  if ((threadIdx.x & 63) == 0) wsum[threadIdx.x >> 6] = s;
  __syncthreads();
  if (threadIdx.x == 0)
    out[0] = (float)((wsum[0] + wsum[1] + wsum[2] + wsum[3]) / (double)N);
}

extern "C" void kernel_launch(void* const* d_in, const int* in_sizes, int n_in,
                              void* d_out, int out_size, void* d_ws, size_t ws_size,
                              hipStream_t stream) {
  const float* x = (const float*)d_in[0];
  const int* labels = (const int*)d_in[1];
  char* ws = (char*)d_ws;
  unsigned char* xb = (unsigned char*)ws;                         // N*KP = 1.9 MB
  float* sq = (float*)(ws + (size_t)N * KP);                      // N*4
  int* lab = (int*)(ws + (size_t)N * KP + (size_t)N * 4);         // N*4
  double* cells = (double*)(ws + (size_t)N * KP + (size_t)N * 8); // 256*8
  float* out = (float*)d_out;

  prep_kernel<<<N / 4, 256, 0, stream>>>(x, labels, xb, sq, lab, cells);
  gram_kernel<<<NBLK, 256, 0, stream>>>(xb, sq, lab, cells);
  reduce_kernel<<<1, 256, 0, stream>>>(cells, out);
}